// Round 5
// baseline (132.635 us; speedup 1.0000x reference)
//
#include <hip/hip_runtime.h>
#include <cstdint>
#include <cstddef>

// Problem constants
#define B_  16
#define C_  384
#define H_  48
#define W_  48
#define HW_ 2304        // 48*48

typedef __bf16 bf16x8 __attribute__((ext_vector_type(8)));
typedef float  f32x4  __attribute__((ext_vector_type(4)));
typedef unsigned short u16x8 __attribute__((ext_vector_type(8)));

typedef __attribute__((address_space(3))) void       lds_void;
typedef const __attribute__((address_space(1))) void gbl_void;

__device__ __forceinline__ unsigned short f2bf(float f) {
    union { float f; unsigned int u; } v; v.f = f;
    unsigned int r = v.u + 0x7fffu + ((v.u >> 16) & 1u);   // RNE
    return (unsigned short)(r >> 16);
}
__device__ __forceinline__ float bf2f(unsigned short u) {
    union { unsigned int u; float f; } v; v.u = ((unsigned int)u) << 16;
    return v.f;
}

// ---------------------------------------------------------------------------
// cast both weight matrices fp32 -> bf16 in one launch.
// ---------------------------------------------------------------------------
__global__ void castw2_kernel(const float* __restrict__ wv, unsigned short* __restrict__ dv,
                              const float* __restrict__ wp, unsigned short* __restrict__ dp) {
    const int blk = blockIdx.x;
    const float* s = (blk < 144) ? wv : wp;
    unsigned short* d = (blk < 144) ? dv : dp;
    const int i = ((blk < 144 ? blk : blk - 144) * 256 + threadIdx.x) * 4;
    const float4 v = *(const float4*)&s[i];
    ushort4 o; o.x = f2bf(v.x); o.y = f2bf(v.y); o.z = f2bf(v.z); o.w = f2bf(v.w);
    *(ushort4*)&d[i] = o;
}

// ---------------------------------------------------------------------------
// transpose-cast: x[b][c][p] fp32 -> xT[b][p][c] bf16.  64x64 tiles via LDS.
// ---------------------------------------------------------------------------
__global__ __launch_bounds__(256) void tcast_kernel(const float* __restrict__ x,
                                                    unsigned short* __restrict__ xT) {
    __shared__ unsigned short tile[64][68];
    const int t  = threadIdx.x;
    const int b  = blockIdx.z;
    const int p0 = blockIdx.x * 64, c0 = blockIdx.y * 64;
    const float* xb = x + ((size_t)b * C_ + c0) * HW_ + p0;

#pragma unroll
    for (int pass = 0; pass < 4; ++pass) {
        const int cr = pass * 16 + (t >> 4);
        const int pc = (t & 15) * 4;
        const float4 v = *(const float4*)&xb[(size_t)cr * HW_ + pc];
        tile[pc + 0][cr] = f2bf(v.x); tile[pc + 1][cr] = f2bf(v.y);
        tile[pc + 2][cr] = f2bf(v.z); tile[pc + 3][cr] = f2bf(v.w);
    }
    __syncthreads();
    unsigned short* xTb = xT + ((size_t)b * HW_ + p0) * C_ + c0;
#pragma unroll
    for (int pass = 0; pass < 4; ++pass) {
        const int pr = pass * 16 + (t >> 4);
        const int cc = (t & 15) * 4;
        *(ushort4*)&xTb[(size_t)pr * C_ + cc] = *(const ushort4*)&tile[pr][cc];
    }
}

// ---------------------------------------------------------------------------
// poolT: 3x3 adaptive avg pool from xT (bf16, channel-last). px[b][c][r].
// ---------------------------------------------------------------------------
__global__ __launch_bounds__(256) void poolT_kernel(const unsigned short* __restrict__ xT,
                                                    float* __restrict__ px) {
    const int r  = blockIdx.x;
    const int c0 = blockIdx.y * 64;
    const int b  = blockIdx.z;
    const int t  = threadIdx.x;
    const int wv = t >> 6;
    const int l  = t & 63;
    const int i  = l >> 3;
    const int cg = l & 7;
    const int ri = r / 3, rj = r % 3;
    const int cbase = c0 + cg * 8;

    __shared__ float s[4][64];

    float acc[8] = {};
#pragma unroll
    for (int k = 0; k < 8; ++k) {
        const int pix = wv * 64 + i + k * 8;
        const int h = ri * 16 + (pix >> 4), w = rj * 16 + (pix & 15);
        const u16x8 v = *(const u16x8*)&xT[((size_t)b * HW_ + h * W_ + w) * C_ + cbase];
#pragma unroll
        for (int e = 0; e < 8; ++e) acc[e] += bf2f(v[e]);
    }
#pragma unroll
    for (int m = 8; m <= 32; m <<= 1)
#pragma unroll
        for (int e = 0; e < 8; ++e) acc[e] += __shfl_xor(acc[e], m, 64);
    if (i == 0)
#pragma unroll
        for (int e = 0; e < 8; ++e) s[wv][cg * 8 + e] = acc[e];
    __syncthreads();
    if (t < 64) {
        const float tot = s[0][t] + s[1][t] + s[2][t] + s[3][t];
        px[((size_t)b * C_ + c0 + t) * 9 + r] = tot * (1.f / 256.f);
    }
}

// ---------------------------------------------------------------------------
// small projections -> kernT[b][q][c] bf16.
// ---------------------------------------------------------------------------
__global__ void small_kernel(const float* __restrict__ px,
                             const float* __restrict__ Wq, const float* __restrict__ bq,
                             const float* __restrict__ Wk, const float* __restrict__ bk,
                             const float* __restrict__ Wg, const float* __restrict__ bg,
                             unsigned short* __restrict__ kernT) {
    const int b = blockIdx.y;
    const int o = blockIdx.x * 128 + threadIdx.x;

    __shared__ float px_l[C_ * 9];
    __shared__ float emb_l[C_];
    __shared__ float wg_l[81];
    __shared__ float bg_l[9];

    for (int idx = threadIdx.x; idx < C_ * 9; idx += 128) px_l[idx] = px[(size_t)b * C_ * 9 + idx];
    if (threadIdx.x < 81) wg_l[threadIdx.x] = Wg[threadIdx.x];
    if (threadIdx.x < 9)  bg_l[threadIdx.x] = bg[threadIdx.x];
    __syncthreads();
    for (int idx = threadIdx.x; idx < C_; idx += 128) {
        float s0 = 0.f;
#pragma unroll
        for (int p = 0; p < 9; ++p) s0 += px_l[idx * 9 + p];
        emb_l[idx] = s0 * (1.f / 9.f);
    }
    __syncthreads();

    float accq[9];
#pragma unroll
    for (int p = 0; p < 9; ++p) accq[p] = bq[o];
    float acck = bk[o];
    const float* wq_row = Wq + (size_t)o * C_;
    const float* wk_row = Wk + (size_t)o * C_;
    for (int i = 0; i < C_; ++i) {
        const float w = wq_row[i];
#pragma unroll
        for (int p = 0; p < 9; ++p) accq[p] = fmaf(w, px_l[i * 9 + p], accq[p]);
        acck = fmaf(wk_row[i], emb_l[i], acck);
    }

    float kf[9], mean = 0.f;
#pragma unroll
    for (int q = 0; q < 9; ++q) {
        float a = bg_l[q];
#pragma unroll
        for (int p = 0; p < 9; ++p) a = fmaf(accq[p], wg_l[q * 9 + p], a);
        kf[q] = a; mean += a;
    }
    mean *= (1.f / 9.f);
    const float sig = 1.f / (1.f + expf(-acck));
#pragma unroll
    for (int q = 0; q < 9; ++q)
        kernT[((size_t)b * 9 + q) * C_ + o] = f2bf(kf[q] - sig * mean);
}

// ---------------------------------------------------------------------------
// bf16 MFMA GEMM — T3-min 2-phase prefetch: BK=32, double-buffered LDS,
// next-step global_load_lds issued BEFORE current ds_read+MFMA, ONE barrier
// per K-step (vmcnt(0)+lgkmcnt(0) folded into __syncthreads).
// T2 swizzle for BK=32: 16B chunk slot ^= (row>>1)&3  (2-way = free).
// XCD-chunked 1-D grid (bijective, gridDim.x % 8 == 0).
// ---------------------------------------------------------------------------
template<int BIAS_COL, bool OUT_BF16, int BMAJOR>
__global__ __launch_bounds__(256) void gemm_bt(const unsigned short* __restrict__ A,
                                               const unsigned short* __restrict__ Bt,
                                               const float* __restrict__ bias,
                                               void* __restrict__ Yv,
                                               int N, int nMt, int nNt, int perB,
                                               long long sA, long long sB, long long sY) {
    const int q8  = gridDim.x >> 3;
    const int swz = (blockIdx.x & 7) * q8 + (blockIdx.x >> 3);
    const int b   = swz / perB;
    const int r   = swz % perB;
    const int mtile = BMAJOR ? (r % nMt) : (r / nNt);
    const int ntile = BMAJOR ? (r / nMt) : (r % nNt);
    const int m0 = mtile * 128, n0 = ntile * 128;

    const int t = threadIdx.x;
    const int l = t & 63, w = t >> 6;
    const unsigned short* Ab = A + (size_t)b * sA;
    const unsigned short* Bb = Bt + (size_t)b * sB;

    // double-buffered: [buf][128 rows][32 bf16], 8 KB per matrix per buf
    __shared__ __align__(16) unsigned short As[2][128 * 32];
    __shared__ __align__(16) unsigned short Bs[2][128 * 32];

    f32x4 acc[4][4] = {};
    const int wm = w >> 1, wn = w & 1;

    // staging: thread t -> rows {64j + (t>>2)}, chunk slot t&3; LDS linear.
    const int srow0 = t >> 2;                    // 0..63
    const int sc    = t & 3;                     // LDS 16B-chunk slot

    // fragment read indices
    const int lr = l & 15;                       // frag row within 16
    const int kq = l >> 4;                       // k-chunk 0..3 (8 bf16 each)

#define STAGE(BUF, K0)                                                          \
    {                                                                           \
        _Pragma("unroll")                                                       \
        for (int j = 0; j < 2; ++j) {                                           \
            const int rw = 64 * j + srow0;                                      \
            const int gk = (sc ^ ((rw >> 1) & 3)) * 8;                          \
            __builtin_amdgcn_global_load_lds(                                   \
                (gbl_void*)(Ab + (size_t)(m0 + rw) * 384 + (K0) + gk),          \
                (lds_void*)(&As[BUF][0] + rw * 32 + sc * 8), 16, 0, 0);         \
        }                                                                       \
        _Pragma("unroll")                                                       \
        for (int j = 0; j < 2; ++j) {                                           \
            const int rw = 64 * j + srow0;                                      \
            const int gk = (sc ^ ((rw >> 1) & 3)) * 8;                          \
            __builtin_amdgcn_global_load_lds(                                   \
                (gbl_void*)(Bb + (size_t)(n0 + rw) * 384 + (K0) + gk),          \
                (lds_void*)(&Bs[BUF][0] + rw * 32 + sc * 8), 16, 0, 0);         \
        }                                                                       \
    }

    // prologue
    STAGE(0, 0);
    __syncthreads();

    int cur = 0;
#pragma unroll 1
    for (int step = 0; step < 12; ++step) {
        if (step < 11) STAGE(cur ^ 1, (step + 1) * 32);   // prefetch next

        const unsigned short* Ac = &As[cur][0];
        const unsigned short* Bc = &Bs[cur][0];
        bf16x8 af[4], bfr[4];
#pragma unroll
        for (int f = 0; f < 4; ++f) {
            const int row = wm * 64 + f * 16 + lr;
            const int ko  = (kq ^ ((row >> 1) & 3)) * 8;
            af[f] = *reinterpret_cast<const bf16x8*>(&Ac[row * 32 + ko]);
        }
#pragma unroll
        for (int f = 0; f < 4; ++f) {
            const int row = wn * 64 + f * 16 + lr;
            const int ko  = (kq ^ ((row >> 1) & 3)) * 8;
            bfr[f] = *reinterpret_cast<const bf16x8*>(&Bc[row * 32 + ko]);
        }
        __builtin_amdgcn_s_setprio(1);
#pragma unroll
        for (int fm = 0; fm < 4; ++fm)
#pragma unroll
            for (int fn = 0; fn < 4; ++fn)
                acc[fm][fn] = __builtin_amdgcn_mfma_f32_16x16x32_bf16(af[fm], bfr[fn], acc[fm][fn], 0, 0, 0);
        __builtin_amdgcn_s_setprio(0);

        __syncthreads();   // per-wave vmcnt(0)+lgkmcnt(0) then barrier
        cur ^= 1;
    }
#undef STAGE

    const int lg = (l >> 4) * 4;
#pragma unroll
    for (int fm = 0; fm < 4; ++fm) {
        const int row = m0 + wm * 64 + fm * 16 + lg;
#pragma unroll
        for (int fn = 0; fn < 4; ++fn) {
            const int col = n0 + wn * 64 + fn * 16 + lr;
            const float cb = BIAS_COL ? bias[col] : 0.f;
#pragma unroll
            for (int rr = 0; rr < 4; ++rr) {
                const float v = acc[fm][fn][rr] + (BIAS_COL ? cb : bias[row + rr]);
                if (OUT_BF16)
                    ((unsigned short*)Yv)[(size_t)b * sY + (size_t)(row + rr) * N + col] = f2bf(v);
                else
                    ((float*)Yv)[(size_t)b * sY + (size_t)(row + rr) * N + col] = v;
            }
        }
    }
}

// ---------------------------------------------------------------------------
// depthwise dynamic 3x3 (channel-last), one thread = one pixel x 8 channels.
// grid (432, 16).
// ---------------------------------------------------------------------------
__global__ __launch_bounds__(256) void dwT_kernel(const unsigned short* __restrict__ vT,
                                                  const unsigned short* __restrict__ kT,
                                                  unsigned short* __restrict__ oT) {
    const int b = blockIdx.y;
    int u = blockIdx.x * 256 + threadIdx.x;
    const int cg = u % 48;
    const int p  = u / 48;
    const int h = p / W_, w = p % W_;
    const int c0 = cg * 8;
    const size_t base = (size_t)b * HW_ * C_;

    u16x8 kv[9];
#pragma unroll
    for (int q = 0; q < 9; ++q)
        kv[q] = *(const u16x8*)&kT[((size_t)b * 9 + q) * C_ + c0];

    float acc[8] = {};
#pragma unroll
    for (int di = 0; di < 3; ++di) {
        const int hh = h + di - 1;
        if (hh < 0 || hh >= H_) continue;
#pragma unroll
        for (int dj = 0; dj < 3; ++dj) {
            const int wn = w + dj - 1;
            if (wn < 0 || wn >= W_) continue;
            const u16x8 v = *(const u16x8*)&vT[base + (size_t)(hh * W_ + wn) * C_ + c0];
            const int q = di * 3 + dj;
#pragma unroll
            for (int e = 0; e < 8; ++e)
                acc[e] = fmaf(bf2f(v[e]), bf2f(kv[q][e]), acc[e]);
        }
    }
    u16x8 o;
#pragma unroll
    for (int e = 0; e < 8; ++e) o[e] = f2bf(acc[e]);
    *(u16x8*)&oT[base + (size_t)p * C_ + c0] = o;
}

// ---------------------------------------------------------------------------
extern "C" void kernel_launch(void* const* d_in, const int* in_sizes, int n_in,
                              void* d_out, int out_size, void* d_ws, size_t ws_size,
                              hipStream_t stream) {
    const float* x  = (const float*)d_in[0];
    const float* Wq = (const float*)d_in[1];
    const float* bq = (const float*)d_in[2];
    const float* Wk = (const float*)d_in[3];
    const float* bk = (const float*)d_in[4];
    const float* Wv = (const float*)d_in[5];
    const float* bv = (const float*)d_in[6];
    const float* Wg = (const float*)d_in[7];
    const float* bg = (const float*)d_in[8];
    const float* Wp = (const float*)d_in[9];
    const float* bp = (const float*)d_in[10];
    float* out = (float*)d_out;

    char* ws = (char*)d_ws;
    const size_t bhwc2 = (size_t)B_ * HW_ * C_ * 2;          // 28,311,552 B
    unsigned short* xT     = (unsigned short*)ws;             // reused as out2T
    unsigned short* valueT = (unsigned short*)(ws + bhwc2);
    unsigned short* Wvb    = (unsigned short*)(ws + 2 * bhwc2);
    unsigned short* Wpb    = (unsigned short*)(ws + 2 * bhwc2 + 294912);
    float*          px     = (float*)(ws + 2 * bhwc2 + 2 * 294912);
    unsigned short* kernT  = (unsigned short*)(ws + 2 * bhwc2 + 2 * 294912 + 221184);
    unsigned short* out2T  = xT;   // xT dead after GEMM1

    castw2_kernel<<<288, 256, 0, stream>>>(Wv, Wvb, Wp, Wpb);
    tcast_kernel<<<dim3(HW_ / 64, C_ / 64, B_), 256, 0, stream>>>(x, xT);
    poolT_kernel<<<dim3(9, C_ / 64, B_), 256, 0, stream>>>(xT, px);
    small_kernel<<<dim3(3, B_), 128, 0, stream>>>(px, Wq, bq, Wk, bk, Wg, bg, kernT);

    // GEMM1: valueT[(b.p)][c] = xT[(b.p)][:] . Wv[c][:] + bv[c]
    gemm_bt<1, true, 0><<<864, 256, 0, stream>>>(
        xT, Wvb, bv, (void*)valueT, C_, 288, 3, 864, 0LL, 0LL, 0LL);

    dwT_kernel<<<dim3(432, B_), 256, 0, stream>>>(valueT, kernT, out2T);

    // GEMM2: out[b][c][p] = Wp[c][:] . out2T[b][p][:] + bp[c]
    gemm_bt<0, false, 1><<<864, 256, 0, stream>>>(
        Wpb, out2T, bp, (void*)out, HW_, 3, 18, 54,
        0LL, (long long)HW_ * C_, (long long)C_ * HW_);
}